// Round 24
// baseline (46.788 us; speedup 1.0000x reference)
//
#include <hip/hip_runtime.h>

#define TT 1024
#define LL 64
#define BB 256             // batch
#define WARM 4             // warm-up steps (contraction <= 0.462/step; r20/r22: absmax 0)
#define NWAVES 8192        // main-kernel waves (2048 blocks x 4) -> 8 waves/SIMD
#define LOG2E 1.44269504088896340736f
#define LN2   0.69314718055994530942f

typedef __fp16 h2 __attribute__((ext_vector_type(2)));
typedef int    i4 __attribute__((ext_vector_type(4)));
__device__ __forceinline__ h2  i2h(int x) { union { int i; h2 h; } u; u.i = x; return u.h; }
__device__ __forceinline__ int h2i(h2 x)  { union { int i; h2 h; } u; u.h = x; return u.i; }

// r22 (champion, 40.0us total, absmax 0) + OCCUPANCY x2 + E-TABLE (r24).
// r22 is chain-latency-bound: per-step serial path (ds_write -> lgkm ->
// 8 broadcast ds_read_b128 -> 8-deep fdot2 chain -> renorm -> pack) ~250cy
// with only 4 waves/SIMD -> VALUBusy 37%. This round:
//  * NWAVES=8192 (2048 blocks x 4; VGPR 56 <= 64 -> 8 waves/SIMD resident):
//    2x independent chains per SIMD. K ~ 16, steps/wave ~ 20.
//  * E-pair table precomputed ONCE by the prefix kernel into d_ws
//    (ejpk[64 cols][32 m] packed f16 pairs, 8 KB, L2-hot): waves load
//    32 dwords instead of 64 scattered trans loads + 64 exp2 + 32 packs —
//    removes the per-wave fixed cost that sank the r14 occupancy attempt.
//
// Structure (proven r13-r22): work_b = max(slen_b-1,1), prefix -> meta,
// K = ceil(W/NWAVES); wave wid owns [wid*K,(wid+1)*K) binary-searched into
// per-seq pieces. Piece [lo,hi): warm-start max(lo-WARM,1); delta =
// A(u@hi-1)-A(u@lo-1) telescopes to log_norm (positive transfer operator,
// Hilbert diam of E=exp(trans) <= 2 -> contraction 0.462/step). lo==1
// exact; slen=1 measures logsumexp(logits[0]) at init. Warm = exactly WARM
// steps when lo>1 with in-warm wave-uniform measure hooks; main =
// guard-free x8 blocks + tail. Rows: rolling 32-bit offset, wrap
// (off+64)&65535 stays in-sequence; wrapped rows never consumed.
// Step: g = exp2(ring*LOG2E) (4 steps old, off-chain); gather = 8 broadcast
// ds_read_b128 via __builtin_memcpy (alias-safe, r22); 32 fdot2; v = s*g;
// exact pow-2 renorm on v_0; pack shfl_xor DPP + cvt_pkrtz; even lanes
// publish pair-word to the per-wave LDS strip (order-pin fence).

__global__ __launch_bounds__(256) void crf_prefix_kernel(
    const int* __restrict__ seq_lens, const float* __restrict__ trans,
    int* __restrict__ meta, int* __restrict__ ejpk)
{
    __shared__ int sbuf[BB];
    const int tid = threadIdx.x;
    int wv = 0;
    if (tid < BB) { int sl = seq_lens[tid]; wv = (sl > 1) ? (sl - 1) : 1; }
    sbuf[tid] = wv;
    __syncthreads();
    for (int off = 1; off < BB; off <<= 1) {
        int v = (tid >= off) ? sbuf[tid - off] : 0;
        __syncthreads();
        sbuf[tid] += v;
        __syncthreads();
    }
    meta[tid + 1] = sbuf[tid];
    if (tid == 0) {
        meta[0] = 0;
        int W = sbuf[BB - 1];
        meta[BB + 1] = (W + NWAVES - 1) / NWAVES;   // K
    }
    // E-pair table: column c, m-range quarter q
    {
        const int c = tid & 63, q = tid >> 6;
        #pragma unroll
        for (int mm = 0; mm < 8; ++mm) {
            int m = 8 * q + mm;
            float e0 = __builtin_amdgcn_exp2f(trans[(2 * m)     * LL + c] * LOG2E);
            float e1 = __builtin_amdgcn_exp2f(trans[(2 * m + 1) * LL + c] * LOG2E);
            ejpk[c * 32 + m] = h2i(__builtin_amdgcn_cvt_pkrtz(e0, e1));
        }
    }
}

__global__ __launch_bounds__(256) void crf_piece_kernel(
    const float* __restrict__ logits,    // [B][T][L]
    const int*   __restrict__ labels,    // [B][T]
    const int*   __restrict__ seq_lens,  // [B]
    const float* __restrict__ trans,     // [L][L]
    const int*   __restrict__ meta,      // [258] prefix + K
    const int*   __restrict__ ejpk,      // [64*32] packed E pairs
    float*       __restrict__ part)      // [NWAVES]
{
    __shared__ __align__(16) int shq[4][32];   // per-wave pair-word strip
    const int wid  = blockIdx.x * 4 + (threadIdx.x >> 6);
    const int lane = threadIdx.x & 63;
    int* const shb = &shq[threadIdx.x >> 6][0];

    // per-wave E-column pairs: 32 dwords from the precomputed table
    int ej[32];
    {
        const int* ejl = ejpk + lane * 32;
        #pragma unroll
        for (int m = 0; m < 32; ++m) ej[m] = ejl[m];
    }

    const int W = meta[BB];
    const int K = meta[BB + 1];
    int g0 = wid * K;
    int g1 = g0 + K; g1 = (g1 < W) ? g1 : W;

#define RENORM(V) { \
    int eb_ = (__builtin_amdgcn_readfirstlane(__float_as_int(V)) >> 23) & 0xFF; \
    C += eb_ - 127; \
    float scl_ = __int_as_float((254 - eb_) << 23); \
    u = (V) * scl_; \
}
// pack + publish: even lane 2k stores pair word (u_2k, u_2k+1) to shb[k];
// memory fence pins program order of this store vs the next step's reads
#define PACKD() { \
    float un_ = __shfl_xor(u, 1, 64); \
    int upk_ = h2i(__builtin_amdgcn_cvt_pkrtz(u, un_)); \
    if (!(lane & 1)) shb[lane >> 1] = upk_; \
    asm volatile("" ::: "memory"); \
}
#define MEAS(OUT) { \
    float us_ = u; \
    _Pragma("unroll") \
    for (int off_ = 32; off_; off_ >>= 1) us_ += __shfl_xor(us_, off_, 64); \
    OUT = ((float)C + __builtin_amdgcn_logf(us_)) * LN2; \
}
// guard-free step on ring slot I: alias-safe broadcast gather + 32 fdot2
#define RS(I) { \
    float g_ = __builtin_amdgcn_exp2f(fR##I * LOG2E); \
    fR##I = lg[ldoff]; \
    ldoff = (ldoff + LL) & (TT * LL - 1); \
    i4 w_[8]; \
    _Pragma("unroll") \
    for (int r_ = 0; r_ < 8; ++r_) \
        __builtin_memcpy(&w_[r_], shb + 4 * r_, 16); \
    float a1_ = 0.f, a2_ = 0.f, a3_ = 0.f, a4_ = 0.f; \
    _Pragma("unroll") \
    for (int r_ = 0; r_ < 8; ++r_) { \
        a1_ = __builtin_amdgcn_fdot2(i2h(w_[r_][0]), i2h(ej[4 * r_]),     a1_, false); \
        a2_ = __builtin_amdgcn_fdot2(i2h(w_[r_][1]), i2h(ej[4 * r_ + 1]), a2_, false); \
        a3_ = __builtin_amdgcn_fdot2(i2h(w_[r_][2]), i2h(ej[4 * r_ + 2]), a3_, false); \
        a4_ = __builtin_amdgcn_fdot2(i2h(w_[r_][3]), i2h(ej[4 * r_ + 3]), a4_, false); \
    } \
    float v_ = ((a1_ + a2_) + (a3_ + a4_)) * g_; \
    RENORM(v_); \
    PACKD(); \
}
// warm step i (t = start + i): RS + wave-uniform measure hooks
#define WS(I, SLOT) { \
    RS(SLOT); \
    if (start + (I) == lo - 1) MEAS(A_in); \
    if (start + (I) == hi - 1) MEAS(A_out); \
}

    float result = 0.f;
    while (g0 < g1) {
        // binary search: largest b with meta[b] <= g0
        int blo = 0, bhi = BB;
        while (bhi - blo > 1) {
            int mid = (blo + bhi) >> 1;
            if (meta[mid] <= g0) blo = mid; else bhi = mid;
        }
        const int b  = blo;
        const int pe = meta[b + 1];
        const int units = ((g1 < pe) ? g1 : pe) - g0;
        const int lo = g0 - meta[b] + 1;
        const int slen = seq_lens[b];
        const int hi = (lo + units < slen) ? (lo + units) : slen;
        const float* lg  = logits + (size_t)b * TT * LL;
        const int*   lab = labels + b * TT;

        // ---- path-score portion for this piece's t-range ----
        float sc = 0.f;
        for (int t0 = lo + lane; t0 < hi; t0 += 64) {
            int l1 = lab[t0];
            sc += lg[(size_t)t0 * LL + l1] + trans[lab[t0 - 1] * LL + l1];
        }
        if (lo == 1 && lane == 0) sc += lg[lab[0]];   // t = 0 unary
        #pragma unroll
        for (int off = 32; off; off >>= 1) sc += __shfl_xor(sc, off, 64);

        const int start = (lo - WARM > 1) ? (lo - WARM) : 1;   // clamped
        const int warmN = (lo > 1) ? WARM : 0;
        int C = 0;
        float u;

        // init u = exp(logit[start-1][lane]); exact when start == 1 (row 0)
        u = __builtin_amdgcn_exp2f(lg[lane + (start - 1) * LL] * LOG2E);
        {   // pin u_0 to [1,2) so the renorm invariant holds from the start
            float v0 = u;
            RENORM(v0);
        }
        PACKD();

        // ring preload rows start..start+3 (in-bounds: start+3 <= 1017)
        unsigned ldoff = (unsigned)(lane + start * LL);
        float fR0 = lg[ldoff]; ldoff += LL;
        float fR1 = lg[ldoff]; ldoff += LL;
        float fR2 = lg[ldoff]; ldoff += LL;
        float fR3 = lg[ldoff]; ldoff += LL;   // next load = row start+4

        float A_in = 0.f, A_out = 0.f;

        // ---- warm phase: exactly WARM steps when lo>1 (slot-aligned) ----
        if (warmN) {
            WS(0, 0); WS(1, 1); WS(2, 2); WS(3, 3);
        }

        // ---- main phase: n guard-free steps; A_out after, iff n>0 ----
        const int n = hi - start - warmN;
        if (n > 0) {
            for (int r = n >> 3; r > 0; --r) {
                RS(0); RS(1); RS(2); RS(3);
                RS(0); RS(1); RS(2); RS(3);
            }
            const int rem = n & 7;
            if (rem > 0) { RS(0);
            if (rem > 1) { RS(1);
            if (rem > 2) { RS(2);
            if (rem > 3) { RS(3);
            if (rem > 4) { RS(0);
            if (rem > 5) { RS(1);
            if (rem > 6) { RS(2); }}}}}}}
            MEAS(A_out);
        } else if (warmN == 0) {
            MEAS(A_out);   // 0-step piece (slen == 1): logsumexp(logits[0])
        }
        // else: A_out already captured in-warm (short piece)

        result += (A_out - A_in) - sc;
        g0 += units;
    }

    if (lane == 0) part[wid] = result;
}

__global__ __launch_bounds__(1024) void reduce_kernel(
    const float* __restrict__ part, float* __restrict__ out)
{
    int tid = threadIdx.x;
    float v = 0.f;
    #pragma unroll
    for (int i = 0; i < 8; ++i) v += part[tid + 1024 * i];
    #pragma unroll
    for (int off = 32; off; off >>= 1) v += __shfl_xor(v, off, 64);
    __shared__ float r[16];
    if ((tid & 63) == 0) r[tid >> 6] = v;
    __syncthreads();
    if (tid == 0) {
        float s = 0.f;
        #pragma unroll
        for (int i = 0; i < 16; ++i) s += r[i];
        out[0] = s;
    }
}

extern "C" void kernel_launch(void* const* d_in, const int* in_sizes, int n_in,
                              void* d_out, int out_size, void* d_ws, size_t ws_size,
                              hipStream_t stream) {
    const float* logits   = (const float*)d_in[0];
    const int*   labels   = (const int*)d_in[1];
    const int*   seq_lens = (const int*)d_in[2];
    const float* trans    = (const float*)d_in[3];

    int*   meta = (int*)d_ws;                         // 258 ints
    int*   ejpk = (int*)((char*)d_ws + 4096);         // 2048 ints (8 KB)
    float* part = (float*)((char*)d_ws + 65536);      // NWAVES floats (32 KB)

    crf_prefix_kernel<<<1, 256, 0, stream>>>(seq_lens, trans, meta, ejpk);
    crf_piece_kernel<<<2048, 256, 0, stream>>>(logits, labels, seq_lens, trans,
                                               meta, ejpk, part);
    reduce_kernel<<<1, 1024, 0, stream>>>(part, (float*)d_out);
}

// Round 25
// 41.282 us; speedup vs baseline: 1.1334x; 1.1334x over previous
//
#include <hip/hip_runtime.h>

#define TT 1024
#define LL 64
#define BB 256             // batch
#define WARM 4             // warm-up steps (contraction <= 0.462/step; r20/r22: absmax 0)
#define NWAVES 4096        // main-kernel waves (1024 blocks x 4) -- r22 champion config
#define LOG2E 1.44269504088896340736f
#define LN2   0.69314718055994530942f

typedef __fp16 h2 __attribute__((ext_vector_type(2)));
typedef int    i4 __attribute__((ext_vector_type(4)));
__device__ __forceinline__ h2  i2h(int x) { union { int i; h2 h; } u; u.i = x; return u.h; }
__device__ __forceinline__ int h2i(h2 x)  { union { int i; h2 h; } u; u.h = x; return u.i; }

// r25 = r22 EXACTLY (champion: 40.0us total, absmax 0.0) + E-TABLE ONLY.
// r23 (half-wave split) and r24 (8 waves/SIMD) both regressed -> r22's
// 4-waves/SIMD serial-chain balance is the local optimum of this
// formulation. The only solo-unmeasured piece of r24 was the E-pair table
// (strictly less per-wave setup): prefix kernel precomputes packed f16
// E-pairs ejpk[64 cols][32 m] (8 KB, L2-hot); each wave loads 32
// contiguous dwords instead of 64 scattered trans loads + 64 exp2 +
// 32 cvt_pkrtz. No structural change.
//
// Structure (proven r13-r22): work_b = max(slen_b-1,1), prefix -> meta,
// K = ceil(W/NWAVES); wave wid owns [wid*K,(wid+1)*K) binary-searched into
// per-seq pieces. Piece [lo,hi): warm-start max(lo-WARM,1); delta =
// A(u@hi-1)-A(u@lo-1) telescopes to log_norm (positive transfer operator,
// Hilbert diam of E=exp(trans) <= 2 -> contraction 0.462/step). lo==1
// exact; slen=1 measures logsumexp(logits[0]) at init. Warm = exactly WARM
// steps when lo>1 with in-warm wave-uniform measure hooks; main =
// guard-free x8 blocks + tail. Rows: rolling 32-bit offset, wrap
// (off+64)&65535 stays in-sequence; wrapped rows never consumed.
// Step: g = exp2(ring*LOG2E) (4 steps old, off-chain); gather = 8 broadcast
// ds_read_b128 via __builtin_memcpy (alias-safe, r22); 32 fdot2; v = s*g;
// exact pow-2 renorm on v_0; pack shfl_xor DPP + cvt_pkrtz; even lanes
// publish pair-word to the per-wave LDS strip (order-pin fence).

__global__ __launch_bounds__(256) void crf_prefix_kernel(
    const int* __restrict__ seq_lens, const float* __restrict__ trans,
    int* __restrict__ meta, int* __restrict__ ejpk)
{
    __shared__ int sbuf[BB];
    const int tid = threadIdx.x;
    int wv = 0;
    if (tid < BB) { int sl = seq_lens[tid]; wv = (sl > 1) ? (sl - 1) : 1; }
    sbuf[tid] = wv;
    __syncthreads();
    for (int off = 1; off < BB; off <<= 1) {
        int v = (tid >= off) ? sbuf[tid - off] : 0;
        __syncthreads();
        sbuf[tid] += v;
        __syncthreads();
    }
    meta[tid + 1] = sbuf[tid];
    if (tid == 0) {
        meta[0] = 0;
        int W = sbuf[BB - 1];
        meta[BB + 1] = (W + NWAVES - 1) / NWAVES;   // K
    }
    // E-pair table: column c = tid&63, quarter q = tid>>6 covers m = 8q..8q+7
    {
        const int c = tid & 63, q = tid >> 6;
        #pragma unroll
        for (int mm = 0; mm < 8; ++mm) {
            int m = 8 * q + mm;
            float e0 = __builtin_amdgcn_exp2f(trans[(2 * m)     * LL + c] * LOG2E);
            float e1 = __builtin_amdgcn_exp2f(trans[(2 * m + 1) * LL + c] * LOG2E);
            ejpk[c * 32 + m] = h2i(__builtin_amdgcn_cvt_pkrtz(e0, e1));
        }
    }
}

__global__ __launch_bounds__(256) void crf_piece_kernel(
    const float* __restrict__ logits,    // [B][T][L]
    const int*   __restrict__ labels,    // [B][T]
    const int*   __restrict__ seq_lens,  // [B]
    const float* __restrict__ trans,     // [L][L]
    const int*   __restrict__ meta,      // [258] prefix + K
    const int*   __restrict__ ejpk,      // [64*32] packed E pairs
    float*       __restrict__ part)      // [NWAVES]
{
    __shared__ __align__(16) int shq[4][32];   // per-wave pair-word strip
    const int wid  = blockIdx.x * 4 + (threadIdx.x >> 6);
    const int lane = threadIdx.x & 63;
    int* const shb = &shq[threadIdx.x >> 6][0];

    // per-wave E-column pairs: 32 contiguous dwords from the table
    int ej[32];
    {
        const int* ejl = ejpk + lane * 32;
        #pragma unroll
        for (int m = 0; m < 32; ++m) ej[m] = ejl[m];
    }

    const int W = meta[BB];
    const int K = meta[BB + 1];
    int g0 = wid * K;
    int g1 = g0 + K; g1 = (g1 < W) ? g1 : W;

#define RENORM(V) { \
    int eb_ = (__builtin_amdgcn_readfirstlane(__float_as_int(V)) >> 23) & 0xFF; \
    C += eb_ - 127; \
    float scl_ = __int_as_float((254 - eb_) << 23); \
    u = (V) * scl_; \
}
// pack + publish: even lane 2k stores pair word (u_2k, u_2k+1) to shb[k];
// memory fence pins program order of this store vs the next step's reads
#define PACKD() { \
    float un_ = __shfl_xor(u, 1, 64); \
    int upk_ = h2i(__builtin_amdgcn_cvt_pkrtz(u, un_)); \
    if (!(lane & 1)) shb[lane >> 1] = upk_; \
    asm volatile("" ::: "memory"); \
}
#define MEAS(OUT) { \
    float us_ = u; \
    _Pragma("unroll") \
    for (int off_ = 32; off_; off_ >>= 1) us_ += __shfl_xor(us_, off_, 64); \
    OUT = ((float)C + __builtin_amdgcn_logf(us_)) * LN2; \
}
// guard-free step on ring slot I: alias-safe broadcast gather + 32 fdot2
#define RS(I) { \
    float g_ = __builtin_amdgcn_exp2f(fR##I * LOG2E); \
    fR##I = lg[ldoff]; \
    ldoff = (ldoff + LL) & (TT * LL - 1); \
    i4 w_[8]; \
    _Pragma("unroll") \
    for (int r_ = 0; r_ < 8; ++r_) \
        __builtin_memcpy(&w_[r_], shb + 4 * r_, 16); \
    float a1_ = 0.f, a2_ = 0.f, a3_ = 0.f, a4_ = 0.f; \
    _Pragma("unroll") \
    for (int r_ = 0; r_ < 8; ++r_) { \
        a1_ = __builtin_amdgcn_fdot2(i2h(w_[r_][0]), i2h(ej[4 * r_]),     a1_, false); \
        a2_ = __builtin_amdgcn_fdot2(i2h(w_[r_][1]), i2h(ej[4 * r_ + 1]), a2_, false); \
        a3_ = __builtin_amdgcn_fdot2(i2h(w_[r_][2]), i2h(ej[4 * r_ + 2]), a3_, false); \
        a4_ = __builtin_amdgcn_fdot2(i2h(w_[r_][3]), i2h(ej[4 * r_ + 3]), a4_, false); \
    } \
    float v_ = ((a1_ + a2_) + (a3_ + a4_)) * g_; \
    RENORM(v_); \
    PACKD(); \
}
// warm step i (t = start + i): RS + wave-uniform measure hooks
#define WS(I, SLOT) { \
    RS(SLOT); \
    if (start + (I) == lo - 1) MEAS(A_in); \
    if (start + (I) == hi - 1) MEAS(A_out); \
}

    float result = 0.f;
    while (g0 < g1) {
        // binary search: largest b with meta[b] <= g0
        int blo = 0, bhi = BB;
        while (bhi - blo > 1) {
            int mid = (blo + bhi) >> 1;
            if (meta[mid] <= g0) blo = mid; else bhi = mid;
        }
        const int b  = blo;
        const int pe = meta[b + 1];
        const int units = ((g1 < pe) ? g1 : pe) - g0;
        const int lo = g0 - meta[b] + 1;
        const int slen = seq_lens[b];
        const int hi = (lo + units < slen) ? (lo + units) : slen;
        const float* lg  = logits + (size_t)b * TT * LL;
        const int*   lab = labels + b * TT;

        // ---- path-score portion for this piece's t-range ----
        float sc = 0.f;
        for (int t0 = lo + lane; t0 < hi; t0 += 64) {
            int l1 = lab[t0];
            sc += lg[(size_t)t0 * LL + l1] + trans[lab[t0 - 1] * LL + l1];
        }
        if (lo == 1 && lane == 0) sc += lg[lab[0]];   // t = 0 unary
        #pragma unroll
        for (int off = 32; off; off >>= 1) sc += __shfl_xor(sc, off, 64);

        const int start = (lo - WARM > 1) ? (lo - WARM) : 1;   // clamped
        const int warmN = (lo > 1) ? WARM : 0;
        int C = 0;
        float u;

        // init u = exp(logit[start-1][lane]); exact when start == 1 (row 0)
        u = __builtin_amdgcn_exp2f(lg[lane + (start - 1) * LL] * LOG2E);
        {   // pin u_0 to [1,2) so the renorm invariant holds from the start
            float v0 = u;
            RENORM(v0);
        }
        PACKD();

        // ring preload rows start..start+3 (in-bounds: start+3 <= 1017)
        unsigned ldoff = (unsigned)(lane + start * LL);
        float fR0 = lg[ldoff]; ldoff += LL;
        float fR1 = lg[ldoff]; ldoff += LL;
        float fR2 = lg[ldoff]; ldoff += LL;
        float fR3 = lg[ldoff]; ldoff += LL;   // next load = row start+4

        float A_in = 0.f, A_out = 0.f;

        // ---- warm phase: exactly WARM steps when lo>1 (slot-aligned) ----
        if (warmN) {
            WS(0, 0); WS(1, 1); WS(2, 2); WS(3, 3);
        }

        // ---- main phase: n guard-free steps; A_out after, iff n>0 ----
        const int n = hi - start - warmN;
        if (n > 0) {
            for (int r = n >> 3; r > 0; --r) {
                RS(0); RS(1); RS(2); RS(3);
                RS(0); RS(1); RS(2); RS(3);
            }
            const int rem = n & 7;
            if (rem > 0) { RS(0);
            if (rem > 1) { RS(1);
            if (rem > 2) { RS(2);
            if (rem > 3) { RS(3);
            if (rem > 4) { RS(0);
            if (rem > 5) { RS(1);
            if (rem > 6) { RS(2); }}}}}}}
            MEAS(A_out);
        } else if (warmN == 0) {
            MEAS(A_out);   // 0-step piece (slen == 1): logsumexp(logits[0])
        }
        // else: A_out already captured in-warm (short piece)

        result += (A_out - A_in) - sc;
        g0 += units;
    }

    if (lane == 0) part[wid] = result;
}

__global__ __launch_bounds__(1024) void reduce_kernel(
    const float* __restrict__ part, float* __restrict__ out)
{
    int tid = threadIdx.x;
    float v = 0.f;
    #pragma unroll
    for (int i = 0; i < 4; ++i) v += part[tid + 1024 * i];
    #pragma unroll
    for (int off = 32; off; off >>= 1) v += __shfl_xor(v, off, 64);
    __shared__ float r[16];
    if ((tid & 63) == 0) r[tid >> 6] = v;
    __syncthreads();
    if (tid == 0) {
        float s = 0.f;
        #pragma unroll
        for (int i = 0; i < 16; ++i) s += r[i];
        out[0] = s;
    }
}

extern "C" void kernel_launch(void* const* d_in, const int* in_sizes, int n_in,
                              void* d_out, int out_size, void* d_ws, size_t ws_size,
                              hipStream_t stream) {
    const float* logits   = (const float*)d_in[0];
    const int*   labels   = (const int*)d_in[1];
    const int*   seq_lens = (const int*)d_in[2];
    const float* trans    = (const float*)d_in[3];

    int*   meta = (int*)d_ws;                         // 258 ints
    int*   ejpk = (int*)((char*)d_ws + 4096);         // 2048 ints (8 KB)
    float* part = (float*)((char*)d_ws + 65536);      // NWAVES floats (16 KB)

    crf_prefix_kernel<<<1, 256, 0, stream>>>(seq_lens, trans, meta, ejpk);
    crf_piece_kernel<<<1024, 256, 0, stream>>>(logits, labels, seq_lens, trans,
                                               meta, ejpk, part);
    reduce_kernel<<<1, 1024, 0, stream>>>(part, (float*)d_out);
}

// Round 26
// 40.118 us; speedup vs baseline: 1.1662x; 1.0290x over previous
//
#include <hip/hip_runtime.h>

#define TT 1024
#define LL 64
#define BB 256             // batch
#define WARM 2             // warm-up steps; empirical contraction ~0.015/step
                           // (WARM=4 -> absmax 0.0 => tau^4*d0 < 1e-7), so
                           // WARM=2 junction error ~5e-4 nats x 4096 ~ 2 abs
#define NWAVES 4096        // main-kernel waves (1024 blocks x 4) -- champion config
#define LOG2E 1.44269504088896340736f
#define LN2   0.69314718055994530942f

typedef __fp16 h2 __attribute__((ext_vector_type(2)));
typedef int    i4 __attribute__((ext_vector_type(4)));
__device__ __forceinline__ h2  i2h(int x) { union { int i; h2 h; } u; u.i = x; return u.h; }
__device__ __forceinline__ int h2i(h2 x)  { union { int i; h2 h; } u; u.h = x; return u.i; }

// r26 = r22 (champion: 40.0us, absmax 0.0) with WARM 4 -> 2 (-5.5% steps).
// Warm block = 2 steps (ring slots 0,1); main loop slot-rotated (2,3,0,1)
// to stay aligned. lo==1 path uses (0,1,2,3). Ring preload offsets wrap
// (&65535) so the never-consumed row start+3 (can reach 1024 at WARM=2)
// stays in-sequence instead of reading past the buffer.
//
// Structure (proven r13-r22): work_b = max(slen_b-1,1), prefix -> meta,
// K = ceil(W/NWAVES); wave wid owns [wid*K,(wid+1)*K) binary-searched into
// per-seq pieces. Piece [lo,hi): warm-start max(lo-WARM,1); delta =
// A(u@hi-1)-A(u@lo-1) telescopes to log_norm (positive transfer operator,
// Hilbert diam of E=exp(trans) <= 2). lo==1 exact; slen=1 measures
// logsumexp(logits[0]) at init. Warm has in-warm wave-uniform measure
// hooks (A_in at t==lo-1; A_out for short pieces at t==hi-1); main =
// guard-free x8 blocks + tail. Rows: rolling 32-bit offset, wrap
// (off+64)&65535 stays in-sequence; wrapped rows never consumed.
// Step: g = exp2(ring*LOG2E) (4 steps old, off-chain); gather = 8 broadcast
// ds_read_b128 via __builtin_memcpy (alias-safe); 32 fdot2; v = s*g; exact
// pow-2 renorm on v_0; pack shfl_xor DPP + cvt_pkrtz; even lanes publish
// pair-word to the per-wave LDS strip (order-pin fence).

__global__ __launch_bounds__(256) void crf_prefix_kernel(
    const int* __restrict__ seq_lens, int* __restrict__ meta)
{
    __shared__ int sbuf[BB];
    const int tid = threadIdx.x;
    int wv = 0;
    if (tid < BB) { int sl = seq_lens[tid]; wv = (sl > 1) ? (sl - 1) : 1; }
    sbuf[tid] = wv;
    __syncthreads();
    for (int off = 1; off < BB; off <<= 1) {
        int v = (tid >= off) ? sbuf[tid - off] : 0;
        __syncthreads();
        sbuf[tid] += v;
        __syncthreads();
    }
    meta[tid + 1] = sbuf[tid];
    if (tid == 0) {
        meta[0] = 0;
        int W = sbuf[BB - 1];
        meta[BB + 1] = (W + NWAVES - 1) / NWAVES;   // K
    }
}

__global__ __launch_bounds__(256) void crf_piece_kernel(
    const float* __restrict__ logits,    // [B][T][L]
    const int*   __restrict__ labels,    // [B][T]
    const int*   __restrict__ seq_lens,  // [B]
    const float* __restrict__ trans,     // [L][L]
    const int*   __restrict__ meta,      // [258] prefix + K
    float*       __restrict__ part)      // [NWAVES]
{
    __shared__ __align__(16) int shq[4][32];   // per-wave pair-word strip
    const int wid  = blockIdx.x * 4 + (threadIdx.x >> 6);
    const int lane = threadIdx.x & 63;
    int* const shb = &shq[threadIdx.x >> 6][0];

    // one-time per wave: E-column pairs for this lane's column j = lane
    int ej[32];
    #pragma unroll
    for (int m = 0; m < 32; ++m) {
        float e0 = __builtin_amdgcn_exp2f(trans[(2 * m)     * LL + lane] * LOG2E);
        float e1 = __builtin_amdgcn_exp2f(trans[(2 * m + 1) * LL + lane] * LOG2E);
        ej[m] = h2i(__builtin_amdgcn_cvt_pkrtz(e0, e1));
    }

    const int W = meta[BB];
    const int K = meta[BB + 1];
    int g0 = wid * K;
    int g1 = g0 + K; g1 = (g1 < W) ? g1 : W;

#define RENORM(V) { \
    int eb_ = (__builtin_amdgcn_readfirstlane(__float_as_int(V)) >> 23) & 0xFF; \
    C += eb_ - 127; \
    float scl_ = __int_as_float((254 - eb_) << 23); \
    u = (V) * scl_; \
}
// pack + publish: even lane 2k stores pair word (u_2k, u_2k+1) to shb[k];
// memory fence pins program order of this store vs the next step's reads
#define PACKD() { \
    float un_ = __shfl_xor(u, 1, 64); \
    int upk_ = h2i(__builtin_amdgcn_cvt_pkrtz(u, un_)); \
    if (!(lane & 1)) shb[lane >> 1] = upk_; \
    asm volatile("" ::: "memory"); \
}
#define MEAS(OUT) { \
    float us_ = u; \
    _Pragma("unroll") \
    for (int off_ = 32; off_; off_ >>= 1) us_ += __shfl_xor(us_, off_, 64); \
    OUT = ((float)C + __builtin_amdgcn_logf(us_)) * LN2; \
}
// guard-free step on ring slot I: alias-safe broadcast gather + 32 fdot2
#define RS(I) { \
    float g_ = __builtin_amdgcn_exp2f(fR##I * LOG2E); \
    fR##I = lg[ldoff]; \
    ldoff = (ldoff + LL) & (TT * LL - 1); \
    i4 w_[8]; \
    _Pragma("unroll") \
    for (int r_ = 0; r_ < 8; ++r_) \
        __builtin_memcpy(&w_[r_], shb + 4 * r_, 16); \
    float a1_ = 0.f, a2_ = 0.f, a3_ = 0.f, a4_ = 0.f; \
    _Pragma("unroll") \
    for (int r_ = 0; r_ < 8; ++r_) { \
        a1_ = __builtin_amdgcn_fdot2(i2h(w_[r_][0]), i2h(ej[4 * r_]),     a1_, false); \
        a2_ = __builtin_amdgcn_fdot2(i2h(w_[r_][1]), i2h(ej[4 * r_ + 1]), a2_, false); \
        a3_ = __builtin_amdgcn_fdot2(i2h(w_[r_][2]), i2h(ej[4 * r_ + 2]), a3_, false); \
        a4_ = __builtin_amdgcn_fdot2(i2h(w_[r_][3]), i2h(ej[4 * r_ + 3]), a4_, false); \
    } \
    float v_ = ((a1_ + a2_) + (a3_ + a4_)) * g_; \
    RENORM(v_); \
    PACKD(); \
}
// warm step i (t = start + i): RS + wave-uniform measure hooks
#define WS(I, SLOT) { \
    RS(SLOT); \
    if (start + (I) == lo - 1) MEAS(A_in); \
    if (start + (I) == hi - 1) MEAS(A_out); \
}
// main loop: n guard-free steps starting at ring slot SA (order SA,SB,SC,SD)
#define MAINLOOP(SA, SB, SC, SD) { \
    for (int r = n >> 3; r > 0; --r) { \
        RS(SA); RS(SB); RS(SC); RS(SD); \
        RS(SA); RS(SB); RS(SC); RS(SD); \
    } \
    const int rem = n & 7; \
    if (rem > 0) { RS(SA); \
    if (rem > 1) { RS(SB); \
    if (rem > 2) { RS(SC); \
    if (rem > 3) { RS(SD); \
    if (rem > 4) { RS(SA); \
    if (rem > 5) { RS(SB); \
    if (rem > 6) { RS(SC); }}}}}}} \
}

    float result = 0.f;
    while (g0 < g1) {
        // binary search: largest b with meta[b] <= g0
        int blo = 0, bhi = BB;
        while (bhi - blo > 1) {
            int mid = (blo + bhi) >> 1;
            if (meta[mid] <= g0) blo = mid; else bhi = mid;
        }
        const int b  = blo;
        const int pe = meta[b + 1];
        const int units = ((g1 < pe) ? g1 : pe) - g0;
        const int lo = g0 - meta[b] + 1;
        const int slen = seq_lens[b];
        const int hi = (lo + units < slen) ? (lo + units) : slen;
        const float* lg  = logits + (size_t)b * TT * LL;
        const int*   lab = labels + b * TT;

        // ---- path-score portion for this piece's t-range ----
        float sc = 0.f;
        for (int t0 = lo + lane; t0 < hi; t0 += 64) {
            int l1 = lab[t0];
            sc += lg[(size_t)t0 * LL + l1] + trans[lab[t0 - 1] * LL + l1];
        }
        if (lo == 1 && lane == 0) sc += lg[lab[0]];   // t = 0 unary
        #pragma unroll
        for (int off = 32; off; off >>= 1) sc += __shfl_xor(sc, off, 64);

        const int start = (lo - WARM > 1) ? (lo - WARM) : 1;   // clamped
        const int warmN = (lo > 1) ? WARM : 0;
        int C = 0;
        float u;

        // init u = exp(logit[start-1][lane]); exact when start == 1 (row 0)
        u = __builtin_amdgcn_exp2f(lg[lane + (start - 1) * LL] * LOG2E);
        {   // pin u_0 to [1,2) so the renorm invariant holds from the start
            float v0 = u;
            RENORM(v0);
        }
        PACKD();

        // ring preload rows start..start+3 with wrap (row start+3 can reach
        // TT at WARM=2; wrapped row is in-sequence and never consumed)
        unsigned ldoff = (unsigned)(lane + start * LL);
        float fR0 = lg[ldoff]; ldoff = (ldoff + LL) & (TT * LL - 1);
        float fR1 = lg[ldoff]; ldoff = (ldoff + LL) & (TT * LL - 1);
        float fR2 = lg[ldoff]; ldoff = (ldoff + LL) & (TT * LL - 1);
        float fR3 = lg[ldoff]; ldoff = (ldoff + LL) & (TT * LL - 1);

        float A_in = 0.f, A_out = 0.f;

        if (warmN) {
            // warm: exactly 2 steps (slots 0,1); A_in fires at t==lo-1
            WS(0, 0); WS(1, 1);
            const int n = hi - start - WARM;
            if (n > 0) {
                MAINLOOP(2, 3, 0, 1);   // ring continues at slot 2
                MEAS(A_out);
            }
            // else: A_out captured in-warm (hi-1 <= start+1)
        } else {
            const int n = hi - start;   // lo == 1, start == 1
            if (n > 0) {
                MAINLOOP(0, 1, 2, 3);
                MEAS(A_out);
            } else {
                MEAS(A_out);   // 0-step piece (slen == 1): logsumexp(logits[0])
            }
        }

        result += (A_out - A_in) - sc;
        g0 += units;
    }

    if (lane == 0) part[wid] = result;
}

__global__ __launch_bounds__(1024) void reduce_kernel(
    const float* __restrict__ part, float* __restrict__ out)
{
    int tid = threadIdx.x;
    float v = 0.f;
    #pragma unroll
    for (int i = 0; i < 4; ++i) v += part[tid + 1024 * i];
    #pragma unroll
    for (int off = 32; off; off >>= 1) v += __shfl_xor(v, off, 64);
    __shared__ float r[16];
    if ((tid & 63) == 0) r[tid >> 6] = v;
    __syncthreads();
    if (tid == 0) {
        float s = 0.f;
        #pragma unroll
        for (int i = 0; i < 16; ++i) s += r[i];
        out[0] = s;
    }
}

extern "C" void kernel_launch(void* const* d_in, const int* in_sizes, int n_in,
                              void* d_out, int out_size, void* d_ws, size_t ws_size,
                              hipStream_t stream) {
    const float* logits   = (const float*)d_in[0];
    const int*   labels   = (const int*)d_in[1];
    const int*   seq_lens = (const int*)d_in[2];
    const float* trans    = (const float*)d_in[3];

    int*   meta = (int*)d_ws;                         // 258 ints (<4 KB)
    float* part = (float*)((char*)d_ws + 4096);       // NWAVES floats (16 KB)

    crf_prefix_kernel<<<1, 256, 0, stream>>>(seq_lens, meta);
    crf_piece_kernel<<<1024, 256, 0, stream>>>(logits, labels, seq_lens, trans,
                                               meta, part);
    reduce_kernel<<<1, 1024, 0, stream>>>(part, (float*)d_out);
}